// Round 2
// baseline (1025.397 us; speedup 1.0000x reference)
//
#include <hip/hip_runtime.h>
#include <stdint.h>

typedef unsigned long long u64;
typedef unsigned int u32;

#define NVERT 300000
#define NTET  1200000
#define NE    (NTET*6)              // 7,200,000 edges
#define TILE  4096
#define NTILES ((NE + TILE - 1)/TILE)   // 1758
#define IDXBITS 23
#define IDXMASK ((1u<<IDXBITS)-1)

// mapping-scatter buckets
#define BSHIFT 16
#define BSZ    65536
#define NBUCK  110                  // ceil(7.2M / 65536)
#define BPB    8                    // blocks per bucket in scatter phase

// output layout (float32 elements)
#define VERTS_OFF 0
#define FACES_OFF 21600000
#define NUMT_OFF  28800000
#define CROSS_OFF 30000000

__constant__ int c_ea[6] = {0,0,0,1,1,2};
__constant__ int c_eb[6] = {1,2,3,2,3,3};
__constant__ int c_numtri[16] = {0,1,1,2,1,2,2,1,1,2,2,1,2,1,1,0};
__constant__ int c_tritab[16][6] = {
 {-1,-1,-1,-1,-1,-1},{1,0,2,-1,-1,-1},{4,0,3,-1,-1,-1},{1,4,2,1,3,4},
 {3,1,5,-1,-1,-1},{2,3,0,2,5,3},{1,4,0,1,5,4},{4,2,5,-1,-1,-1},
 {4,5,2,-1,-1,-1},{4,1,0,4,5,1},{3,2,0,3,5,2},{1,3,5,-1,-1,-1},
 {4,1,2,4,3,1},{3,0,4,-1,-1,-1},{2,0,1,-1,-1,-1},{-1,-1,-1,-1,-1,-1}};

// LDS swizzle for u64 keys[4096]: spread stride-16 accesses across bank pairs
__device__ __forceinline__ int sw(int j){ return j ^ ((j >> 4) & 15); }

__global__ void k_pack(const int* __restrict__ tet, u64* __restrict__ dst){
  int i = blockIdx.x*blockDim.x + threadIdx.x;
  if (i >= NE) return;
  int t = i/6, k = i - t*6;
  int a = tet[t*4 + c_ea[k]];
  int b = tet[t*4 + c_eb[k]];
  int e0 = min(a,b), e1 = max(a,b);
  u64 code = (u64)e0 * NVERT + (u64)e1;
  dst[i] = (code << IDXBITS) | (u64)i;
}

__global__ void k_hist(const u64* __restrict__ src, u32* __restrict__ hist, int shift){
  __shared__ u32 h[256];
  int tid = threadIdx.x;
  h[tid] = 0; __syncthreads();
  int base = blockIdx.x * TILE;
  for (int k=0;k<16;k++){
    int i = base + k*256 + tid;
    if (i < NE){
      u32 d = (u32)((src[i] >> shift) & 255);
      atomicAdd(&h[d], 1u);
    }
  }
  __syncthreads();
  hist[tid * NTILES + blockIdx.x] = h[tid];
}

// per-digit exclusive scan across tiles (in place), digit totals out
__global__ void k_scan_digit(u32* __restrict__ hist, u32* __restrict__ digitTot){
  __shared__ u32 s[256];
  int d = blockIdx.x, tid = threadIdx.x;
  u32* row = hist + (size_t)d * NTILES;
  u32 carry = 0;
  for (int start=0; start<NTILES; start+=256){
    int idx = start + tid;
    u32 x = (idx < NTILES) ? row[idx] : 0;
    s[tid] = x; __syncthreads();
    for (int off=1; off<256; off<<=1){
      u32 t = (tid >= off) ? s[tid-off] : 0;
      __syncthreads();
      s[tid] += t;
      __syncthreads();
    }
    u32 incl = s[tid];
    u32 tot  = s[255];
    if (idx < NTILES) row[idx] = carry + incl - x;
    carry += tot;
    __syncthreads();
  }
  if (tid==0) digitTot[d] = carry;
}

__global__ void k_scan_base(const u32* __restrict__ digitTot, u32* __restrict__ digitOff){
  __shared__ u32 s[256];
  int tid = threadIdx.x;
  u32 x = digitTot[tid];
  s[tid]=x; __syncthreads();
  for (int off=1; off<256; off<<=1){
    u32 t=(tid>=off)?s[tid-off]:0;
    __syncthreads();
    s[tid]+=t;
    __syncthreads();
  }
  digitOff[tid] = s[tid]-x;
}

__global__ __launch_bounds__(256) void k_scatter(const u64* __restrict__ src, u64* __restrict__ dst,
      const u32* __restrict__ hist, const u32* __restrict__ digitOff, int shift){
  __shared__ u64 keys[TILE];
  __shared__ u32 sc[256];
  __shared__ u32 lstart[256];
  int tid = threadIdx.x;
  int base = blockIdx.x * TILE;
  for (int k=0;k<16;k++){
    int j = k*256 + tid;
    int i = base + j;
    keys[sw(j)] = (i < NE) ? src[i] : ~0ull;
  }
  __syncthreads();
  // 8 stable 1-bit splits -> tile sorted by this pass's digit
  for (int q=0;q<8;q++){
    int sh = shift + q;
    u64 myk[16];
    u32 ones = 0, mask = 0;
    #pragma unroll
    for (int k=0;k<16;k++){
      myk[k] = keys[sw(tid*16+k)];
      u32 b = (u32)((myk[k] >> sh) & 1);
      mask |= b << k;
      ones += b;
    }
    sc[tid] = ones; __syncthreads();
    for (int off=1; off<256; off<<=1){
      u32 t=(tid>=off)?sc[tid-off]:0;
      __syncthreads();
      sc[tid]+=t;
      __syncthreads();
    }
    u32 incl = sc[tid];
    u32 totalOnes = sc[255];
    __syncthreads();
    u32 onesBefore = incl - ones;
    u32 zerosBefore = (u32)(tid*16) - onesBefore;
    u32 Z = TILE - totalOnes;
    #pragma unroll
    for (int k=0;k<16;k++){
      u32 pos;
      if ((mask>>k)&1u){ pos = Z + onesBefore; onesBefore++; }
      else { pos = zerosBefore; zerosBefore++; }
      keys[sw((int)pos)] = myk[k];
    }
    __syncthreads();
  }
  // local run starts per digit
  for (int k=0;k<16;k++){
    int j = k*256+tid;
    u32 d = (u32)((keys[sw(j)] >> shift) & 255);
    bool headj = (j==0) || (((keys[sw(j-1)] >> shift) & 255) != d);
    if (headj) lstart[d] = (u32)j;
  }
  __syncthreads();
  for (int k=0;k<16;k++){
    int j = k*256+tid;
    u64 key = keys[sw(j)];
    if (key == ~0ull) continue;  // padding
    u32 d = (u32)((key >> shift) & 255);
    u32 gpos = digitOff[d] + hist[(size_t)d*NTILES + blockIdx.x] + (u32)j - lstart[d];
    dst[gpos] = key;
  }
}

// per-tile sums of (head, head&cross) over sorted array
__global__ void k_flag_tilesum(const u64* __restrict__ A, const float* __restrict__ sdf,
                               u64* __restrict__ tileSums){
  __shared__ u64 s[256];
  int tid = threadIdx.x;
  int base = blockIdx.x*TILE;
  u32 th=0, tc=0;
  for (int k=0;k<16;k++){
    int i = base + k*256 + tid;
    if (i < NE){
      u64 v = A[i];
      u64 code = v >> IDXBITS;
      bool head = (i==0) || ((A[i-1] >> IDXBITS) != code);
      if (head){
        u32 u0 = (u32)(code / NVERT), u1 = (u32)(code % NVERT);
        bool cross = (sdf[u0] > 0.f) != (sdf[u1] > 0.f);
        th++; if (cross) tc++;
      }
    }
  }
  s[tid] = ((u64)th<<32) | (u64)tc;
  __syncthreads();
  for (int off=128; off>0; off>>=1){
    if (tid<off) s[tid]+=s[tid+off];
    __syncthreads();
  }
  if (tid==0) tileSums[blockIdx.x] = s[0];
}

__global__ void k_scan_tiles(u64* __restrict__ tileSums, u64* __restrict__ tileOff){
  __shared__ u64 s[256];
  int tid = threadIdx.x;
  u64 carry=0;
  for (int start=0; start<NTILES; start+=256){
    int idx=start+tid;
    u64 x = (idx<NTILES)? tileSums[idx] : 0;
    s[tid]=x; __syncthreads();
    for (int off=1;off<256;off<<=1){
      u64 t=(tid>=off)?s[tid-off]:0;
      __syncthreads();
      s[tid]+=t;
      __syncthreads();
    }
    u64 incl=s[tid], tot=s[255];
    if (idx<NTILES) tileOff[idx] = carry + incl - x;
    carry += tot;
    __syncthreads();
  }
}

// scan + bucketed append of (orig, m) pairs; also writes crossing flags
__global__ __launch_bounds__(256) void k_emit_map(const u64* __restrict__ A, const float* __restrict__ sdf,
     const u64* __restrict__ tileOff, u64* __restrict__ pairs, u32* __restrict__ cursors,
     float* __restrict__ crossing_out){
  __shared__ u64 s[256];
  __shared__ u32 cnt[NBUCK];
  __shared__ u32 cur[NBUCK];
  int tid=threadIdx.x;
  int base = blockIdx.x*TILE;
  int start = base + tid*16;
  u32 headm=0, crossm=0;
  u32 orig16[16];
  #pragma unroll
  for (int k=0;k<16;k++){
    int i = start + k;
    u64 v = 0;
    if (i<NE){
      v = A[i];
      u64 code = v>>IDXBITS;
      bool head = (i==0) || ((A[i-1]>>IDXBITS) != code);
      u32 u0=(u32)(code/NVERT), u1=(u32)(code%NVERT);
      bool cross = (sdf[u0]>0.f) != (sdf[u1]>0.f);
      if (head) headm |= 1u<<k;
      if (cross) crossm |= 1u<<k;
    }
    orig16[k] = (u32)(v & IDXMASK);
  }
  u32 th = __popc(headm), tc = __popc(headm & crossm);
  u64 x = ((u64)th<<32)|(u64)tc;
  s[tid]=x; __syncthreads();
  for (int off=1;off<256;off<<=1){
    u64 t=(tid>=off)?s[tid-off]:0;
    __syncthreads();
    s[tid]+=t;
    __syncthreads();
  }
  u64 excl = s[tid]-x;
  u64 baseOff = tileOff[blockIdx.x] + excl;
  u32 H = (u32)(baseOff>>32), C=(u32)(baseOff & 0xFFFFFFFFull);
  int m16[16];
  #pragma unroll
  for (int k=0;k<16;k++){
    int i = start+k;
    if (i<NE){
      bool head = (headm>>k)&1u;
      bool cross = (crossm>>k)&1u;
      if (head){ H++; if(cross) C++; }
      m16[k] = cross ? (int)C-1 : -1;
      if (head) crossing_out[H-1] = cross ? 1.f : 0.f;
    } else m16[k] = -2;
  }
  // bucketed append
  if (tid < NBUCK){ cnt[tid] = 0; }
  __syncthreads();
  #pragma unroll
  for (int k=0;k<16;k++){
    if (start+k < NE) atomicAdd(&cnt[orig16[k]>>BSHIFT], 1u);
  }
  __syncthreads();
  if (tid < NBUCK) cur[tid] = atomicAdd(&cursors[tid], cnt[tid]);
  __syncthreads();
  #pragma unroll
  for (int k=0;k<16;k++){
    if (start+k < NE){
      u32 b = orig16[k]>>BSHIFT;
      u32 slot = atomicAdd(&cur[b], 1u);
      pairs[(size_t)b*BSZ + slot] = ((u64)orig16[k]<<32) | (u64)(u32)m16[k];
    }
  }
}

// per-bucket scatter of mapping, window = 256KB of mapF -> L2-resident
__global__ void k_map_scatter(const u64* __restrict__ pairs, float* __restrict__ mapF){
  int b = blockIdx.x / BPB, sub = blockIdx.x % BPB;
  int bsz = min(BSZ, NE - b*BSZ);
  const u64* p = pairs + (size_t)b*BSZ;
  const int per = BSZ/BPB;           // 8192
  for (int k=0;k<per/256;k++){
    int i = sub*per + k*256 + threadIdx.x;
    if (i < bsz){
      u64 v = p[i];
      mapF[(u32)(v>>32)] = (float)(int)(u32)v;
    }
  }
}

// re-walk sorted array, write interpolated verts at crossing heads
__global__ __launch_bounds__(256) void k_emit_verts(const u64* __restrict__ A, const float* __restrict__ sdf,
     const float* __restrict__ pos, const u64* __restrict__ tileOff, float* __restrict__ verts){
  __shared__ u64 s[256];
  int tid=threadIdx.x;
  int base = blockIdx.x*TILE;
  int start = base + tid*16;
  u64 myk[16];
  u32 headm=0, crossm=0;
  #pragma unroll
  for (int k=0;k<16;k++){
    int i = start + k;
    u64 v = 0;
    if (i<NE){
      v = A[i];
      u64 code = v>>IDXBITS;
      bool head = (i==0) || ((A[i-1]>>IDXBITS) != code);
      u32 u0=(u32)(code/NVERT), u1=(u32)(code%NVERT);
      bool cross = (sdf[u0]>0.f) != (sdf[u1]>0.f);
      if (head) headm |= 1u<<k;
      if (cross) crossm |= 1u<<k;
    }
    myk[k]=v;
  }
  u32 th = __popc(headm), tc = __popc(headm & crossm);
  u64 x = ((u64)th<<32)|(u64)tc;
  s[tid]=x; __syncthreads();
  for (int off=1;off<256;off<<=1){
    u64 t=(tid>=off)?s[tid-off]:0;
    __syncthreads();
    s[tid]+=t;
    __syncthreads();
  }
  u64 excl = s[tid]-x;
  u64 baseOff = tileOff[blockIdx.x] + excl;
  u32 C=(u32)(baseOff & 0xFFFFFFFFull);
  #pragma unroll
  for (int k=0;k<16;k++){
    int i = start+k;
    if (i>=NE) break;
    bool head = (headm>>k)&1u;
    bool cross = (crossm>>k)&1u;
    if (head && cross){
      C++;
      int m = (int)C-1;
      u64 code = myk[k]>>IDXBITS;
      u32 u0=(u32)(code/NVERT), u1=(u32)(code%NVERT);
      float s0=sdf[u0], s1=sdf[u1];
      float denom = s0-s1;
      float w0 = (-s1)/denom, w1 = s0/denom;
      verts[3*m+0] = pos[u0*3+0]*w0 + pos[u1*3+0]*w1;
      verts[3*m+1] = pos[u0*3+1]*w0 + pos[u1*3+1]*w1;
      verts[3*m+2] = pos[u0*3+2]*w0 + pos[u1*3+2]*w1;
    }
  }
}

__global__ void k_faces(const int* __restrict__ tet, const float* __restrict__ sdf,
                        float* faceRegion, float* __restrict__ numt){
  int t = blockIdx.x*blockDim.x + threadIdx.x;
  if (t>=NTET) return;
  int occ=0;
  #pragma unroll
  for (int j=0;j<4;j++){ int v=tet[t*4+j]; if (sdf[v]>0.f) occ |= 1<<j; }
  int ntri = c_numtri[occ];
  float em[6];
  #pragma unroll
  for (int j=0;j<6;j++) em[j] = faceRegion[t*6+j];   // edge mapping written by k_map_scatter
  float f[6];
  #pragma unroll
  for (int j=0;j<6;j++){
    int tri = c_tritab[occ][j];
    f[j] = ((j/3) < ntri) ? em[tri] : -1.f;
  }
  #pragma unroll
  for (int j=0;j<6;j++) faceRegion[t*6+j] = f[j];
  numt[t] = (float)ntri;
}

extern "C" void kernel_launch(void* const* d_in, const int* in_sizes, int n_in,
                              void* d_out, int out_size, void* d_ws, size_t ws_size,
                              hipStream_t stream) {
  const float* pos = (const float*)d_in[0];
  const float* sdf = (const float*)d_in[1];
  const int*   tet = (const int*)d_in[2];
  float* out = (float*)d_out;

  // ws layout
  u64* bufA     = (u64*)d_ws;                                        // 57,600,000 B
  u32* hist     = (u32*)((char*)d_ws + 57600000);                    // 1,800,192 B
  u32* digitTot = (u32*)((char*)d_ws + 57600000 + 1800192);          // 1024 B
  u32* digitOff = digitTot + 256;                                    // 1024 B
  u64* tileSums = (u64*)((char*)d_ws + 57600000 + 1800192 + 2048);   // NTILES*8
  u64* tileOff  = tileSums + NTILES;                                 // NTILES*8
  u32* cursors  = (u32*)(tileOff + NTILES);                          // NBUCK*4
  // d_out's first region doubles as sort buffer B / pairs buffer
  u64* bufB = (u64*)d_out;
  u64* pairs = (u64*)d_out;

  k_pack<<<(NE+255)/256, 256, 0, stream>>>(tet, bufB);

  u64 *src = bufB, *dst = bufA;
  for (int p=0; p<5; p++){
    int shift = IDXBITS + 8*p;
    k_hist<<<NTILES, 256, 0, stream>>>(src, hist, shift);
    k_scan_digit<<<256, 256, 0, stream>>>(hist, digitTot);
    k_scan_base<<<1, 256, 0, stream>>>(digitTot, digitOff);
    k_scatter<<<NTILES, 256, 0, stream>>>(src, dst, hist, digitOff, shift);
    u64* tmp = src; src = dst; dst = tmp;
  }
  // after 5 passes the sorted array lives in bufA

  hipMemsetAsync(out + CROSS_OFF, 0, (size_t)7200000*4, stream);   // crossing
  hipMemsetAsync(cursors, 0, NBUCK*sizeof(u32), stream);

  k_flag_tilesum<<<NTILES, 256, 0, stream>>>(bufA, sdf, tileSums);
  k_scan_tiles<<<1, 256, 0, stream>>>(tileSums, tileOff);

  k_emit_map<<<NTILES, 256, 0, stream>>>(bufA, sdf, tileOff, pairs, cursors, out + CROSS_OFF);
  k_map_scatter<<<NBUCK*BPB, 256, 0, stream>>>(pairs, out + FACES_OFF);

  hipMemsetAsync(out + VERTS_OFF, 0, (size_t)21600000*4, stream);  // verts (after pairs consumed)
  k_emit_verts<<<NTILES, 256, 0, stream>>>(bufA, sdf, pos, tileOff, out + VERTS_OFF);

  k_faces<<<(NTET+255)/256, 256, 0, stream>>>(tet, sdf, out + FACES_OFF, out + NUMT_OFF);
}

// Round 3
// 967.487 us; speedup vs baseline: 1.0599x; 1.0599x over previous
//
#include <hip/hip_runtime.h>
#include <stdint.h>

typedef unsigned long long u64;
typedef unsigned int u32;

#define NVERT 300000
#define NTET  1200000
#define NE    (NTET*6)              // 7,200,000 edges
#define TILE  4096
#define NTILES ((NE + TILE - 1)/TILE)   // 1758
#define IDXBITS 23
#define IDXMASK ((1u<<IDXBITS)-1)

// mapping-scatter buckets
#define BSHIFT 16
#define BSZ    65536
#define NBUCK  110                  // ceil(7.2M / 65536)
#define BPB    8

// output layout (float32 elements)
#define VERTS_OFF 0
#define FACES_OFF 21600000
#define NUMT_OFF  28800000
#define CROSS_OFF 30000000

__constant__ int c_ea[6] = {0,0,0,1,1,2};
__constant__ int c_eb[6] = {1,2,3,2,3,3};
__constant__ int c_numtri[16] = {0,1,1,2,1,2,2,1,1,2,2,1,2,1,1,0};
__constant__ int c_tritab[16][6] = {
 {-1,-1,-1,-1,-1,-1},{1,0,2,-1,-1,-1},{4,0,3,-1,-1,-1},{1,4,2,1,3,4},
 {3,1,5,-1,-1,-1},{2,3,0,2,5,3},{1,4,0,1,5,4},{4,2,5,-1,-1,-1},
 {4,5,2,-1,-1,-1},{4,1,0,4,5,1},{3,2,0,3,5,2},{1,3,5,-1,-1,-1},
 {4,1,2,4,3,1},{3,0,4,-1,-1,-1},{2,0,1,-1,-1,-1},{-1,-1,-1,-1,-1,-1}};

__device__ __forceinline__ int sw(int j){ return j ^ ((j >> 4) & 15); }

__global__ void k_pack(const int* __restrict__ tet, u64* __restrict__ dst){
  int i = blockIdx.x*blockDim.x + threadIdx.x;
  if (i >= NE) return;
  int t = i/6, k = i - t*6;
  int a = tet[t*4 + c_ea[k]];
  int b = tet[t*4 + c_eb[k]];
  int e0 = min(a,b), e1 = max(a,b);
  u64 code = (u64)e0 * NVERT + (u64)e1;
  dst[i] = (code << IDXBITS) | (u64)i;
}

__global__ void k_psd(const float* __restrict__ pos, const float* __restrict__ sdf,
                      float4* __restrict__ psd){
  int v = blockIdx.x*blockDim.x + threadIdx.x;
  if (v < NVERT) psd[v] = make_float4(pos[3*v], pos[3*v+1], pos[3*v+2], sdf[v]);
}

__global__ void k_hist(const u64* __restrict__ src, u32* __restrict__ hist, int shift){
  __shared__ u32 h[256];
  int tid = threadIdx.x;
  h[tid] = 0; __syncthreads();
  int base = blockIdx.x * TILE;
  for (int k=0;k<16;k++){
    int i = base + k*256 + tid;
    if (i < NE){
      u32 d = (u32)((src[i] >> shift) & 255);
      atomicAdd(&h[d], 1u);
    }
  }
  __syncthreads();
  hist[tid * NTILES + blockIdx.x] = h[tid];
}

__global__ void k_scan_digit(u32* __restrict__ hist, u32* __restrict__ digitTot){
  __shared__ u32 s[256];
  int d = blockIdx.x, tid = threadIdx.x;
  u32* row = hist + (size_t)d * NTILES;
  u32 carry = 0;
  for (int start=0; start<NTILES; start+=256){
    int idx = start + tid;
    u32 x = (idx < NTILES) ? row[idx] : 0;
    s[tid] = x; __syncthreads();
    for (int off=1; off<256; off<<=1){
      u32 t = (tid >= off) ? s[tid-off] : 0;
      __syncthreads();
      s[tid] += t;
      __syncthreads();
    }
    u32 incl = s[tid];
    u32 tot  = s[255];
    if (idx < NTILES) row[idx] = carry + incl - x;
    carry += tot;
    __syncthreads();
  }
  if (tid==0) digitTot[d] = carry;
}

__global__ void k_scan_base(const u32* __restrict__ digitTot, u32* __restrict__ digitOff){
  __shared__ u32 s[256];
  int tid = threadIdx.x;
  u32 x = digitTot[tid];
  s[tid]=x; __syncthreads();
  for (int off=1; off<256; off<<=1){
    u32 t=(tid>=off)?s[tid-off]:0;
    __syncthreads();
    s[tid]+=t;
    __syncthreads();
  }
  digitOff[tid] = s[tid]-x;
}

__global__ __launch_bounds__(256) void k_scatter(const u64* __restrict__ src, u64* __restrict__ dst,
      const u32* __restrict__ hist, const u32* __restrict__ digitOff, int shift){
  __shared__ u64 keys[TILE];
  __shared__ u32 sc[256];
  __shared__ u32 lstart[256];
  int tid = threadIdx.x;
  int base = blockIdx.x * TILE;
  for (int k=0;k<16;k++){
    int j = k*256 + tid;
    int i = base + j;
    keys[sw(j)] = (i < NE) ? src[i] : ~0ull;
  }
  __syncthreads();
  for (int q=0;q<8;q++){
    int sh = shift + q;
    u64 myk[16];
    u32 ones = 0, mask = 0;
    #pragma unroll
    for (int k=0;k<16;k++){
      myk[k] = keys[sw(tid*16+k)];
      u32 b = (u32)((myk[k] >> sh) & 1);
      mask |= b << k;
      ones += b;
    }
    sc[tid] = ones; __syncthreads();
    for (int off=1; off<256; off<<=1){
      u32 t=(tid>=off)?sc[tid-off]:0;
      __syncthreads();
      sc[tid]+=t;
      __syncthreads();
    }
    u32 incl = sc[tid];
    u32 totalOnes = sc[255];
    __syncthreads();
    u32 onesBefore = incl - ones;
    u32 zerosBefore = (u32)(tid*16) - onesBefore;
    u32 Z = TILE - totalOnes;
    #pragma unroll
    for (int k=0;k<16;k++){
      u32 pos;
      if ((mask>>k)&1u){ pos = Z + onesBefore; onesBefore++; }
      else { pos = zerosBefore; zerosBefore++; }
      keys[sw((int)pos)] = myk[k];
    }
    __syncthreads();
  }
  for (int k=0;k<16;k++){
    int j = k*256+tid;
    u32 d = (u32)((keys[sw(j)] >> shift) & 255);
    bool headj = (j==0) || (((keys[sw(j-1)] >> shift) & 255) != d);
    if (headj) lstart[d] = (u32)j;
  }
  __syncthreads();
  for (int k=0;k<16;k++){
    int j = k*256+tid;
    u64 key = keys[sw(j)];
    if (key == ~0ull) continue;
    u32 d = (u32)((key >> shift) & 255);
    u32 gpos = digitOff[d] + hist[(size_t)d*NTILES + blockIdx.x] + (u32)j - lstart[d];
    dst[gpos] = key;
  }
}

// ---------- FAST PATH: single fused post-sort pass (decoupled lookback) ----------
// lb[t] packs: status(2b, bits 62-63) | headCount(23b, bits 23-45) | crossCount(23b, bits 0-22)
__global__ __launch_bounds__(256) void k_emit_all(const u64* __restrict__ A,
     const float4* __restrict__ psd, u64* __restrict__ lb,
     u64* __restrict__ pairs, u32* __restrict__ cursors,
     float* __restrict__ verts, float* __restrict__ crossing_out){
  __shared__ u64 s[256];
  __shared__ u32 cnt[NBUCK];
  __shared__ u32 cur[NBUCK];
  __shared__ u64 bcast;
  int tid=threadIdx.x, blk=blockIdx.x;
  int start = blk*TILE + tid*16;
  u64 myk[16];
  u32 headm=0, crossm=0;
  #pragma unroll
  for (int k=0;k<16;k++){
    int i = start + k;
    u64 v = 0;
    if (i<NE){
      v = A[i];
      u64 code = v>>IDXBITS;
      bool head = (i==0) || ((A[i-1]>>IDXBITS) != code);
      u32 u0=(u32)(code/NVERT), u1=(u32)(code%NVERT);
      bool cross = (psd[u0].w>0.f) != (psd[u1].w>0.f);
      if (head) headm |= 1u<<k;
      if (cross) crossm |= 1u<<k;
    }
    myk[k]=v;
  }
  u32 th = __popc(headm), tc = __popc(headm & crossm);
  u64 x = ((u64)th<<32)|(u64)tc;
  s[tid]=x; __syncthreads();
  for (int off=1;off<256;off<<=1){
    u64 t=(tid>=off)?s[tid-off]:0;
    __syncthreads();
    s[tid]+=t;
    __syncthreads();
  }
  u64 excl = s[tid]-x;
  u64 tot  = s[255];
  // bucket counts (overlap with lookback latency)
  if (tid < NBUCK) cnt[tid] = 0;
  __syncthreads();
  #pragma unroll
  for (int k=0;k<16;k++){
    if (start+k < NE) atomicAdd(&cnt[(u32)(myk[k] & IDXMASK)>>BSHIFT], 1u);
  }
  if (tid==255){
    u32 thT=(u32)(tot>>32), tcT=(u32)tot;
    u64 pth=0, ptc=0;
    if (blk==0){
      atomicExch(&lb[0], (2ull<<62)|((u64)thT<<23)|(u64)tcT);
    } else {
      atomicExch(&lb[blk], (1ull<<62)|((u64)thT<<23)|(u64)tcT);
      int p=blk-1;
      while (true){
        u64 v = atomicAdd(&lb[p], 0ull);
        u64 st = v>>62;
        if (st==0){ __builtin_amdgcn_s_sleep(1); continue; }
        pth += (v>>23)&0x7FFFFFull;
        ptc += v & 0x7FFFFFull;
        if (st==2) break;
        p--;
      }
      atomicExch(&lb[blk], (2ull<<62)|((u64)(thT+(u32)pth)<<23)|(u64)(tcT+(u32)ptc));
    }
    bcast = (pth<<32)|ptc;
  }
  __syncthreads();
  if (tid < NBUCK) cur[tid] = atomicAdd(&cursors[tid], cnt[tid]);
  __syncthreads();
  u64 pfx = bcast;
  u32 H = (u32)(pfx>>32) + (u32)(excl>>32);
  u32 C = (u32)pfx + (u32)excl;
  #pragma unroll
  for (int k=0;k<16;k++){
    int i = start+k;
    if (i>=NE) break;
    bool head  = (headm>>k)&1u;
    bool cross = (crossm>>k)&1u;
    if (head){ H++; if(cross) C++; }
    int m = cross ? (int)C-1 : -1;
    u32 orig = (u32)(myk[k] & IDXMASK);
    u32 b = orig>>BSHIFT;
    u32 slot = atomicAdd(&cur[b], 1u);
    pairs[(size_t)b*BSZ + slot] = ((u64)orig<<32) | (u64)(u32)m;
    if (head){
      crossing_out[H-1] = cross ? 1.f : 0.f;
      if (cross){
        u64 code = myk[k]>>IDXBITS;
        u32 u0=(u32)(code/NVERT), u1=(u32)(code%NVERT);
        float4 a = psd[u0], bb = psd[u1];
        float denom = a.w - bb.w;
        float w0 = (-bb.w)/denom, w1 = a.w/denom;
        verts[3*m+0] = a.x*w0 + bb.x*w1;
        verts[3*m+1] = a.y*w0 + bb.y*w1;
        verts[3*m+2] = a.z*w0 + bb.z*w1;
      }
    }
  }
}

// ---------- FALLBACK-PATH kernels (round-2 choreography) ----------
__global__ void k_flag_tilesum(const u64* __restrict__ A, const float* __restrict__ sdf,
                               u64* __restrict__ tileSums){
  __shared__ u64 s[256];
  int tid = threadIdx.x;
  int base = blockIdx.x*TILE;
  u32 th=0, tc=0;
  for (int k=0;k<16;k++){
    int i = base + k*256 + tid;
    if (i < NE){
      u64 v = A[i];
      u64 code = v >> IDXBITS;
      bool head = (i==0) || ((A[i-1] >> IDXBITS) != code);
      if (head){
        u32 u0 = (u32)(code / NVERT), u1 = (u32)(code % NVERT);
        bool cross = (sdf[u0] > 0.f) != (sdf[u1] > 0.f);
        th++; if (cross) tc++;
      }
    }
  }
  s[tid] = ((u64)th<<32) | (u64)tc;
  __syncthreads();
  for (int off=128; off>0; off>>=1){
    if (tid<off) s[tid]+=s[tid+off];
    __syncthreads();
  }
  if (tid==0) tileSums[blockIdx.x] = s[0];
}

__global__ void k_scan_tiles(u64* __restrict__ tileSums, u64* __restrict__ tileOff){
  __shared__ u64 s[256];
  int tid = threadIdx.x;
  u64 carry=0;
  for (int start=0; start<NTILES; start+=256){
    int idx=start+tid;
    u64 x = (idx<NTILES)? tileSums[idx] : 0;
    s[tid]=x; __syncthreads();
    for (int off=1;off<256;off<<=1){
      u64 t=(tid>=off)?s[tid-off]:0;
      __syncthreads();
      s[tid]+=t;
      __syncthreads();
    }
    u64 incl=s[tid], tot=s[255];
    if (idx<NTILES) tileOff[idx] = carry + incl - x;
    carry += tot;
    __syncthreads();
  }
}

__global__ __launch_bounds__(256) void k_emit_map(const u64* __restrict__ A, const float* __restrict__ sdf,
     const u64* __restrict__ tileOff, u64* __restrict__ pairs, u32* __restrict__ cursors,
     float* __restrict__ crossing_out){
  __shared__ u64 s[256];
  __shared__ u32 cnt[NBUCK];
  __shared__ u32 cur[NBUCK];
  int tid=threadIdx.x;
  int base = blockIdx.x*TILE;
  int start = base + tid*16;
  u32 headm=0, crossm=0;
  u32 orig16[16];
  #pragma unroll
  for (int k=0;k<16;k++){
    int i = start + k;
    u64 v = 0;
    if (i<NE){
      v = A[i];
      u64 code = v>>IDXBITS;
      bool head = (i==0) || ((A[i-1]>>IDXBITS) != code);
      u32 u0=(u32)(code/NVERT), u1=(u32)(code%NVERT);
      bool cross = (sdf[u0]>0.f) != (sdf[u1]>0.f);
      if (head) headm |= 1u<<k;
      if (cross) crossm |= 1u<<k;
    }
    orig16[k] = (u32)(v & IDXMASK);
  }
  u32 th = __popc(headm), tc = __popc(headm & crossm);
  u64 x = ((u64)th<<32)|(u64)tc;
  s[tid]=x; __syncthreads();
  for (int off=1;off<256;off<<=1){
    u64 t=(tid>=off)?s[tid-off]:0;
    __syncthreads();
    s[tid]+=t;
    __syncthreads();
  }
  u64 excl = s[tid]-x;
  u64 baseOff = tileOff[blockIdx.x] + excl;
  u32 H = (u32)(baseOff>>32), C=(u32)(baseOff & 0xFFFFFFFFull);
  int m16[16];
  #pragma unroll
  for (int k=0;k<16;k++){
    int i = start+k;
    if (i<NE){
      bool head = (headm>>k)&1u;
      bool cross = (crossm>>k)&1u;
      if (head){ H++; if(cross) C++; }
      m16[k] = cross ? (int)C-1 : -1;
      if (head) crossing_out[H-1] = cross ? 1.f : 0.f;
    } else m16[k] = -2;
  }
  if (tid < NBUCK){ cnt[tid] = 0; }
  __syncthreads();
  #pragma unroll
  for (int k=0;k<16;k++){
    if (start+k < NE) atomicAdd(&cnt[orig16[k]>>BSHIFT], 1u);
  }
  __syncthreads();
  if (tid < NBUCK) cur[tid] = atomicAdd(&cursors[tid], cnt[tid]);
  __syncthreads();
  #pragma unroll
  for (int k=0;k<16;k++){
    if (start+k < NE){
      u32 b = orig16[k]>>BSHIFT;
      u32 slot = atomicAdd(&cur[b], 1u);
      pairs[(size_t)b*BSZ + slot] = ((u64)orig16[k]<<32) | (u64)(u32)m16[k];
    }
  }
}

__global__ void k_map_scatter(const u64* __restrict__ pairs, float* __restrict__ mapF){
  int b = blockIdx.x / BPB, sub = blockIdx.x % BPB;
  int bsz = min(BSZ, NE - b*BSZ);
  const u64* p = pairs + (size_t)b*BSZ;
  const int per = BSZ/BPB;
  for (int k=0;k<per/256;k++){
    int i = sub*per + k*256 + threadIdx.x;
    if (i < bsz){
      u64 v = p[i];
      mapF[(u32)(v>>32)] = (float)(int)(u32)v;
    }
  }
}

__global__ __launch_bounds__(256) void k_emit_verts(const u64* __restrict__ A, const float* __restrict__ sdf,
     const float* __restrict__ pos, const u64* __restrict__ tileOff, float* __restrict__ verts){
  __shared__ u64 s[256];
  int tid=threadIdx.x;
  int base = blockIdx.x*TILE;
  int start = base + tid*16;
  u64 myk[16];
  u32 headm=0, crossm=0;
  #pragma unroll
  for (int k=0;k<16;k++){
    int i = start + k;
    u64 v = 0;
    if (i<NE){
      v = A[i];
      u64 code = v>>IDXBITS;
      bool head = (i==0) || ((A[i-1]>>IDXBITS) != code);
      u32 u0=(u32)(code/NVERT), u1=(u32)(code%NVERT);
      bool cross = (sdf[u0]>0.f) != (sdf[u1]>0.f);
      if (head) headm |= 1u<<k;
      if (cross) crossm |= 1u<<k;
    }
    myk[k]=v;
  }
  u32 th = __popc(headm), tc = __popc(headm & crossm);
  u64 x = ((u64)th<<32)|(u64)tc;
  s[tid]=x; __syncthreads();
  for (int off=1;off<256;off<<=1){
    u64 t=(tid>=off)?s[tid-off]:0;
    __syncthreads();
    s[tid]+=t;
    __syncthreads();
  }
  u64 excl = s[tid]-x;
  u64 baseOff = tileOff[blockIdx.x] + excl;
  u32 C=(u32)(baseOff & 0xFFFFFFFFull);
  #pragma unroll
  for (int k=0;k<16;k++){
    int i = start+k;
    if (i>=NE) break;
    bool head = (headm>>k)&1u;
    bool cross = (crossm>>k)&1u;
    if (head && cross){
      C++;
      int m = (int)C-1;
      u64 code = myk[k]>>IDXBITS;
      u32 u0=(u32)(code/NVERT), u1=(u32)(code%NVERT);
      float s0=sdf[u0], s1=sdf[u1];
      float denom = s0-s1;
      float w0 = (-s1)/denom, w1 = s0/denom;
      verts[3*m+0] = pos[u0*3+0]*w0 + pos[u1*3+0]*w1;
      verts[3*m+1] = pos[u0*3+1]*w0 + pos[u1*3+1]*w1;
      verts[3*m+2] = pos[u0*3+2]*w0 + pos[u1*3+2]*w1;
    }
  }
}

__global__ void k_faces(const int* __restrict__ tet, const float* __restrict__ sdf,
                        float* faceRegion, float* __restrict__ numt){
  int t = blockIdx.x*blockDim.x + threadIdx.x;
  if (t>=NTET) return;
  int occ=0;
  #pragma unroll
  for (int j=0;j<4;j++){ int v=tet[t*4+j]; if (sdf[v]>0.f) occ |= 1<<j; }
  int ntri = c_numtri[occ];
  float em[6];
  #pragma unroll
  for (int j=0;j<6;j++) em[j] = faceRegion[t*6+j];
  float f[6];
  #pragma unroll
  for (int j=0;j<6;j++){
    int tri = c_tritab[occ][j];
    f[j] = ((j/3) < ntri) ? em[tri] : -1.f;
  }
  #pragma unroll
  for (int j=0;j<6;j++) faceRegion[t*6+j] = f[j];
  numt[t] = (float)ntri;
}

extern "C" void kernel_launch(void* const* d_in, const int* in_sizes, int n_in,
                              void* d_out, int out_size, void* d_ws, size_t ws_size,
                              hipStream_t stream) {
  const float* pos = (const float*)d_in[0];
  const float* sdf = (const float*)d_in[1];
  const int*   tet = (const int*)d_in[2];
  float* out = (float*)d_out;

  // common ws layout
  char* w = (char*)d_ws;
  u64* bufA     = (u64*)w;                         // 57,600,000
  u32* hist     = (u32*)(w + 57600000);            // 1,800,192
  u32* digitTot = (u32*)(w + 59400192);            // 1024
  u32* digitOff = (u32*)(w + 59401216);            // 1024
  u64* lb       = (u64*)(w + 59402240);            // NTILES*8 = 14,064
  u32* cursors  = (u32*)(w + 59416320);            // 440
  float4* psd   = (float4*)(w + 59416832);         // 4,800,000
  u64* pairs_ws = (u64*)(w + 64216832);            // 57,600,000 -> ends 121,816,832
  // fallback misc (aliases lb region is fine — different path)
  u64* tileSums = (u64*)(w + 59402240);
  u64* tileOff  = tileSums + NTILES;

  u64* bufB = (u64*)d_out;   // sort ping buffer in d_out (dead data until rewritten)

  const bool fast = (ws_size >= 121816832ull);

  k_pack<<<(NE+255)/256, 256, 0, stream>>>(tet, bufB);
  if (fast) k_psd<<<(NVERT+255)/256, 256, 0, stream>>>(pos, sdf, psd);

  u64 *src = bufB, *dst = bufA;
  for (int p=0; p<5; p++){
    int shift = IDXBITS + 8*p;
    k_hist<<<NTILES, 256, 0, stream>>>(src, hist, shift);
    k_scan_digit<<<256, 256, 0, stream>>>(hist, digitTot);
    k_scan_base<<<1, 256, 0, stream>>>(digitTot, digitOff);
    k_scatter<<<NTILES, 256, 0, stream>>>(src, dst, hist, digitOff, shift);
    u64* tmp = src; src = dst; dst = tmp;
  }
  // sorted array now in bufA (ws)

  if (fast){
    hipMemsetAsync(out + VERTS_OFF, 0, (size_t)21600000*4, stream);
    hipMemsetAsync(out + CROSS_OFF, 0, (size_t)7200000*4, stream);
    hipMemsetAsync(cursors, 0, NBUCK*sizeof(u32), stream);
    hipMemsetAsync(lb, 0, (size_t)NTILES*8, stream);
    k_emit_all<<<NTILES, 256, 0, stream>>>(bufA, psd, lb, pairs_ws, cursors,
                                           out + VERTS_OFF, out + CROSS_OFF);
    k_map_scatter<<<NBUCK*BPB, 256, 0, stream>>>(pairs_ws, out + FACES_OFF);
    k_faces<<<(NTET+255)/256, 256, 0, stream>>>(tet, sdf, out + FACES_OFF, out + NUMT_OFF);
  } else {
    u64* pairs = (u64*)d_out;
    hipMemsetAsync(out + CROSS_OFF, 0, (size_t)7200000*4, stream);
    hipMemsetAsync(cursors, 0, NBUCK*sizeof(u32), stream);
    k_flag_tilesum<<<NTILES, 256, 0, stream>>>(bufA, sdf, tileSums);
    k_scan_tiles<<<1, 256, 0, stream>>>(tileSums, tileOff);
    k_emit_map<<<NTILES, 256, 0, stream>>>(bufA, sdf, tileOff, pairs, cursors, out + CROSS_OFF);
    k_map_scatter<<<NBUCK*BPB, 256, 0, stream>>>(pairs, out + FACES_OFF);
    hipMemsetAsync(out + VERTS_OFF, 0, (size_t)21600000*4, stream);
    k_emit_verts<<<NTILES, 256, 0, stream>>>(bufA, sdf, pos, tileOff, out + VERTS_OFF);
    k_faces<<<(NTET+255)/256, 256, 0, stream>>>(tet, sdf, out + FACES_OFF, out + NUMT_OFF);
  }
}

// Round 4
// 939.769 us; speedup vs baseline: 1.0911x; 1.0295x over previous
//
#include <hip/hip_runtime.h>
#include <stdint.h>

typedef unsigned long long u64;
typedef unsigned int u32;

#define NVERT 300000
#define NTET  1200000
#define NE    (NTET*6)              // 7,200,000 edges
#define TILE  4096
#define NTILES ((NE + TILE - 1)/TILE)   // 1758
#define IDXBITS 23
#define IDXMASK ((1u<<IDXBITS)-1)
#define CODESHIFT 24                // key = code<<24 | cross<<23 | idx

// mapping-scatter buckets
#define BSHIFT 16
#define BSZ    65536
#define NBUCK  110
#define BPB    8

// output layout (float32 elements)
#define VERTS_OFF 0
#define FACES_OFF 21600000
#define NUMT_OFF  28800000
#define CROSS_OFF 30000000

__constant__ int c_ea[6] = {0,0,0,1,1,2};
__constant__ int c_eb[6] = {1,2,3,2,3,3};
__constant__ int c_numtri[16] = {0,1,1,2,1,2,2,1,1,2,2,1,2,1,1,0};
__constant__ int c_tritab[16][6] = {
 {-1,-1,-1,-1,-1,-1},{1,0,2,-1,-1,-1},{4,0,3,-1,-1,-1},{1,4,2,1,3,4},
 {3,1,5,-1,-1,-1},{2,3,0,2,5,3},{1,4,0,1,5,4},{4,2,5,-1,-1,-1},
 {4,5,2,-1,-1,-1},{4,1,0,4,5,1},{3,2,0,3,5,2},{1,3,5,-1,-1,-1},
 {4,1,2,4,3,1},{3,0,4,-1,-1,-1},{2,0,1,-1,-1,-1},{-1,-1,-1,-1,-1,-1}};

__device__ __forceinline__ int sw(int j){ return j ^ ((j >> 4) & 15); }

// one thread per TET: 6 keys with embedded cross bit + occ nibble (as float, into NUMT region)
__global__ void k_pack(const int* __restrict__ tet, const float* __restrict__ sdf,
                       u64* __restrict__ dst, float* __restrict__ occF){
  int t = blockIdx.x*blockDim.x + threadIdx.x;
  if (t >= NTET) return;
  int4 q = ((const int4*)tet)[t];
  int v[4] = {q.x, q.y, q.z, q.w};
  u32 o[4];
  int occ = 0;
  #pragma unroll
  for (int j=0;j<4;j++){ o[j] = sdf[v[j]] > 0.f ? 1u : 0u; occ |= (int)o[j] << j; }
  occF[t] = (float)occ;
  u64 base = (u64)t*6;
  #pragma unroll
  for (int k=0;k<6;k++){
    int a = v[c_ea[k]], b = v[c_eb[k]];
    u64 cross = (o[c_ea[k]] != o[c_eb[k]]) ? 1ull : 0ull;
    int e0 = min(a,b), e1 = max(a,b);
    u64 code = (u64)e0 * NVERT + (u64)e1;
    dst[base+k] = (code << CODESHIFT) | (cross << IDXBITS) | (base + (u64)k);
  }
}

__global__ void k_psd(const float* __restrict__ pos, const float* __restrict__ sdf,
                      float4* __restrict__ psd){
  int v = blockIdx.x*blockDim.x + threadIdx.x;
  if (v < NVERT) psd[v] = make_float4(pos[3*v], pos[3*v+1], pos[3*v+2], sdf[v]);
}

__global__ void k_hist(const u64* __restrict__ src, u32* __restrict__ hist, int shift){
  __shared__ u32 h[256];
  int tid = threadIdx.x;
  h[tid] = 0; __syncthreads();
  int base = blockIdx.x * TILE;
  for (int k=0;k<16;k++){
    int i = base + k*256 + tid;
    if (i < NE){
      u32 d = (u32)((src[i] >> shift) & 255);
      atomicAdd(&h[d], 1u);
    }
  }
  __syncthreads();
  hist[tid * NTILES + blockIdx.x] = h[tid];
}

__global__ void k_scan_digit(u32* __restrict__ hist, u32* __restrict__ digitTot){
  __shared__ u32 s[256];
  int d = blockIdx.x, tid = threadIdx.x;
  u32* row = hist + (size_t)d * NTILES;
  u32 carry = 0;
  for (int start=0; start<NTILES; start+=256){
    int idx = start + tid;
    u32 x = (idx < NTILES) ? row[idx] : 0;
    s[tid] = x; __syncthreads();
    for (int off=1; off<256; off<<=1){
      u32 t = (tid >= off) ? s[tid-off] : 0;
      __syncthreads();
      s[tid] += t;
      __syncthreads();
    }
    u32 incl = s[tid];
    u32 tot  = s[255];
    if (idx < NTILES) row[idx] = carry + incl - x;
    carry += tot;
    __syncthreads();
  }
  if (tid==0) digitTot[d] = carry;
}

__global__ void k_scan_base(const u32* __restrict__ digitTot, u32* __restrict__ digitOff){
  __shared__ u32 s[256];
  int tid = threadIdx.x;
  u32 x = digitTot[tid];
  s[tid]=x; __syncthreads();
  for (int off=1; off<256; off<<=1){
    u32 t=(tid>=off)?s[tid-off]:0;
    __syncthreads();
    s[tid]+=t;
    __syncthreads();
  }
  digitOff[tid] = s[tid]-x;
}

__global__ __launch_bounds__(256) void k_scatter(const u64* __restrict__ src, u64* __restrict__ dst,
      const u32* __restrict__ hist, const u32* __restrict__ digitOff, int shift){
  __shared__ u64 keys[TILE];
  __shared__ u32 sc[256];
  __shared__ u32 lstart[256];
  int tid = threadIdx.x;
  int base = blockIdx.x * TILE;
  for (int k=0;k<16;k++){
    int j = k*256 + tid;
    int i = base + j;
    keys[sw(j)] = (i < NE) ? src[i] : ~0ull;
  }
  __syncthreads();
  for (int q=0;q<8;q++){
    int sh = shift + q;
    u64 myk[16];
    u32 ones = 0, mask = 0;
    #pragma unroll
    for (int k=0;k<16;k++){
      myk[k] = keys[sw(tid*16+k)];
      u32 b = (u32)((myk[k] >> sh) & 1);
      mask |= b << k;
      ones += b;
    }
    sc[tid] = ones; __syncthreads();
    for (int off=1; off<256; off<<=1){
      u32 t=(tid>=off)?sc[tid-off]:0;
      __syncthreads();
      sc[tid]+=t;
      __syncthreads();
    }
    u32 incl = sc[tid];
    u32 totalOnes = sc[255];
    __syncthreads();
    u32 onesBefore = incl - ones;
    u32 zerosBefore = (u32)(tid*16) - onesBefore;
    u32 Z = TILE - totalOnes;
    #pragma unroll
    for (int k=0;k<16;k++){
      u32 pos;
      if ((mask>>k)&1u){ pos = Z + onesBefore; onesBefore++; }
      else { pos = zerosBefore; zerosBefore++; }
      keys[sw((int)pos)] = myk[k];
    }
    __syncthreads();
  }
  for (int k=0;k<16;k++){
    int j = k*256+tid;
    u32 d = (u32)((keys[sw(j)] >> shift) & 255);
    bool headj = (j==0) || (((keys[sw(j-1)] >> shift) & 255) != d);
    if (headj) lstart[d] = (u32)j;
  }
  __syncthreads();
  for (int k=0;k<16;k++){
    int j = k*256+tid;
    u64 key = keys[sw(j)];
    if (key == ~0ull) continue;
    u32 d = (u32)((key >> shift) & 255);
    u32 gpos = digitOff[d] + hist[(size_t)d*NTILES + blockIdx.x] + (u32)j - lstart[d];
    dst[gpos] = key;
  }
}

// fused post-sort pass, decoupled lookback; cross bit read from the key
__global__ __launch_bounds__(256) void k_emit_all(const u64* __restrict__ A,
     const float4* __restrict__ psd, u64* __restrict__ lb,
     u64* __restrict__ pairs, u32* __restrict__ cursors,
     float* __restrict__ verts, float* __restrict__ crossing_out){
  __shared__ u64 s[256];
  __shared__ u32 cnt[NBUCK];
  __shared__ u32 cur[NBUCK];
  __shared__ u64 bcast;
  int tid=threadIdx.x, blk=blockIdx.x;
  int start = blk*TILE + tid*16;
  u64 prev = (start > 0 && start <= NE) ? A[start-1] : ~0ull;
  u64 myk[16];
  u32 headm=0, crossm=0;
  if (tid < NBUCK) cnt[tid] = 0;
  #pragma unroll
  for (int k=0;k<16;k++){
    int i = start + k;
    u64 v = 0;
    if (i<NE){
      v = A[i];
      if ((v>>CODESHIFT) != (prev>>CODESHIFT)) headm |= 1u<<k;
      if ((v>>IDXBITS) & 1ull) crossm |= 1u<<k;
      prev = v;
    }
    myk[k]=v;
  }
  __syncthreads();
  #pragma unroll
  for (int k=0;k<16;k++){
    if (start+k < NE) atomicAdd(&cnt[((u32)myk[k] & IDXMASK)>>BSHIFT], 1u);
  }
  u32 th = __popc(headm), tc = __popc(headm & crossm);
  u64 x = ((u64)th<<32)|(u64)tc;
  s[tid]=x; __syncthreads();
  for (int off=1;off<256;off<<=1){
    u64 t=(tid>=off)?s[tid-off]:0;
    __syncthreads();
    s[tid]+=t;
    __syncthreads();
  }
  u64 excl = s[tid]-x;
  u64 tot  = s[255];
  if (tid==255){
    u32 thT=(u32)(tot>>32), tcT=(u32)tot;
    u64 pth=0, ptc=0;
    if (blk==0){
      atomicExch(&lb[0], (2ull<<62)|((u64)thT<<23)|(u64)tcT);
    } else {
      atomicExch(&lb[blk], (1ull<<62)|((u64)thT<<23)|(u64)tcT);
      int p=blk-1;
      while (true){
        u64 v = atomicAdd(&lb[p], 0ull);
        u64 st = v>>62;
        if (st==0){ __builtin_amdgcn_s_sleep(1); continue; }
        pth += (v>>23)&0x7FFFFFull;
        ptc += v & 0x7FFFFFull;
        if (st==2) break;
        p--;
      }
      atomicExch(&lb[blk], (2ull<<62)|((u64)(thT+(u32)pth)<<23)|(u64)(tcT+(u32)ptc));
    }
    bcast = (pth<<32)|ptc;
  }
  __syncthreads();
  if (tid < NBUCK) cur[tid] = atomicAdd(&cursors[tid], cnt[tid]);
  __syncthreads();
  u64 pfx = bcast;
  u32 H = (u32)(pfx>>32) + (u32)(excl>>32);
  u32 C = (u32)pfx + (u32)excl;
  #pragma unroll
  for (int k=0;k<16;k++){
    int i = start+k;
    if (i>=NE) break;
    bool head  = (headm>>k)&1u;
    bool cross = (crossm>>k)&1u;
    if (head){ H++; if(cross) C++; }
    int m = cross ? (int)C-1 : -1;
    u32 orig = (u32)myk[k] & IDXMASK;
    u32 b = orig>>BSHIFT;
    u32 slot = atomicAdd(&cur[b], 1u);
    pairs[(size_t)b*BSZ + slot] = ((u64)orig<<32) | (u64)(u32)m;
    if (head){
      crossing_out[H-1] = cross ? 1.f : 0.f;
      if (cross){
        u64 code = myk[k]>>CODESHIFT;
        u32 u0=(u32)(code/NVERT), u1=(u32)(code%NVERT);
        float4 a = psd[u0], bb = psd[u1];
        float denom = a.w - bb.w;
        float w0 = (-bb.w)/denom, w1 = a.w/denom;
        verts[3*m+0] = a.x*w0 + bb.x*w1;
        verts[3*m+1] = a.y*w0 + bb.y*w1;
        verts[3*m+2] = a.z*w0 + bb.z*w1;
      }
    }
  }
}

__global__ void k_map_scatter(const u64* __restrict__ pairs, float* __restrict__ mapF){
  int b = blockIdx.x / BPB, sub = blockIdx.x % BPB;
  int bsz = min(BSZ, NE - b*BSZ);
  const u64* p = pairs + (size_t)b*BSZ;
  const int per = BSZ/BPB;
  for (int k=0;k<per/256;k++){
    int i = sub*per + k*256 + threadIdx.x;
    if (i < bsz){
      u64 v = p[i];
      mapF[(u32)(v>>32)] = (float)(int)(u32)v;
    }
  }
}

// occF (== numt region) read, then overwritten per-element by the same thread
__global__ void k_faces(const float* __restrict__ occF, float* faceRegion, float* __restrict__ numt){
  int t = blockIdx.x*blockDim.x + threadIdx.x;
  if (t>=NTET) return;
  int occ = (int)occF[t];
  int ntri = c_numtri[occ];
  float em[6];
  #pragma unroll
  for (int j=0;j<6;j++) em[j] = faceRegion[t*6+j];
  float f[6];
  #pragma unroll
  for (int j=0;j<6;j++){
    int tri = c_tritab[occ][j];
    f[j] = ((j/3) < ntri) ? em[tri] : -1.f;
  }
  #pragma unroll
  for (int j=0;j<6;j++) faceRegion[t*6+j] = f[j];
  numt[t] = (float)ntri;
}

extern "C" void kernel_launch(void* const* d_in, const int* in_sizes, int n_in,
                              void* d_out, int out_size, void* d_ws, size_t ws_size,
                              hipStream_t stream) {
  const float* pos = (const float*)d_in[0];
  const float* sdf = (const float*)d_in[1];
  const int*   tet = (const int*)d_in[2];
  float* out = (float*)d_out;

  // ws layout
  char* w = (char*)d_ws;
  u64* bufA     = (u64*)w;                         // 57,600,000
  u32* hist     = (u32*)(w + 57600000);            // 1,800,192
  u32* digitTot = (u32*)(w + 59400192);            // 1024
  u32* digitOff = (u32*)(w + 59401216);            // 1024
  u64* lb       = (u64*)(w + 59402240);            // 14,064
  u32* cursors  = (u32*)(w + 59416320);            // 440
  float4* psd   = (float4*)(w + 59416832);         // 4,800,000
  u64* pairs_ws = (u64*)(w + 64216832);            // 57,600,000 -> ends 121,816,832

  u64* bufB = (u64*)d_out;   // first 57.6MB of d_out as sort ping buffer

  k_pack<<<(NTET+255)/256, 256, 0, stream>>>(tet, sdf, bufB, out + NUMT_OFF);
  k_psd<<<(NVERT+255)/256, 256, 0, stream>>>(pos, sdf, psd);

  u64 *src = bufB, *dst = bufA;
  for (int p=0; p<5; p++){
    int shift = IDXBITS + 8*p;
    k_hist<<<NTILES, 256, 0, stream>>>(src, hist, shift);
    k_scan_digit<<<256, 256, 0, stream>>>(hist, digitTot);
    k_scan_base<<<1, 256, 0, stream>>>(digitTot, digitOff);
    k_scatter<<<NTILES, 256, 0, stream>>>(src, dst, hist, digitOff, shift);
    u64* tmp = src; src = dst; dst = tmp;
  }
  // sorted array now in bufA

  hipMemsetAsync(out + VERTS_OFF, 0, (size_t)21600000*4, stream);
  hipMemsetAsync(out + CROSS_OFF, 0, (size_t)7200000*4, stream);
  hipMemsetAsync(cursors, 0, NBUCK*sizeof(u32), stream);
  hipMemsetAsync(lb, 0, (size_t)NTILES*8, stream);

  k_emit_all<<<NTILES, 256, 0, stream>>>(bufA, psd, lb, pairs_ws, cursors,
                                         out + VERTS_OFF, out + CROSS_OFF);
  k_map_scatter<<<NBUCK*BPB, 256, 0, stream>>>(pairs_ws, out + FACES_OFF);
  k_faces<<<(NTET+255)/256, 256, 0, stream>>>(out + NUMT_OFF, out + FACES_OFF, out + NUMT_OFF);
}

// Round 5
// 817.603 us; speedup vs baseline: 1.2542x; 1.1494x over previous
//
#include <hip/hip_runtime.h>
#include <stdint.h>

typedef unsigned long long u64;
typedef unsigned int u32;

#define NVERT 300000
#define NTET  1200000
#define NE    (NTET*6)              // 7,200,000 edges
#define TILE  4096
#define NTILES ((NE + TILE - 1)/TILE)   // 1758
#define IDXBITS 23
#define IDXMASK ((1u<<IDXBITS)-1)
#define CODESHIFT 24                // key = code<<24 | cross<<23 | idx
#define RBITS 10
#define RBINS 1024
#define SORT_BASE 24                // sort code bits only (bits 24..63)

// mapping-scatter buckets
#define BSHIFT 16
#define BSZ    65536
#define NBUCK  110
#define BPB    8

// output layout (float32 elements)
#define VERTS_OFF 0
#define FACES_OFF 21600000
#define NUMT_OFF  28800000
#define CROSS_OFF 30000000

__constant__ int c_ea[6] = {0,0,0,1,1,2};
__constant__ int c_eb[6] = {1,2,3,2,3,3};
__constant__ int c_numtri[16] = {0,1,1,2,1,2,2,1,1,2,2,1,2,1,1,0};
__constant__ int c_tritab[16][6] = {
 {-1,-1,-1,-1,-1,-1},{1,0,2,-1,-1,-1},{4,0,3,-1,-1,-1},{1,4,2,1,3,4},
 {3,1,5,-1,-1,-1},{2,3,0,2,5,3},{1,4,0,1,5,4},{4,2,5,-1,-1,-1},
 {4,5,2,-1,-1,-1},{4,1,0,4,5,1},{3,2,0,3,5,2},{1,3,5,-1,-1,-1},
 {4,1,2,4,3,1},{3,0,4,-1,-1,-1},{2,0,1,-1,-1,-1},{-1,-1,-1,-1,-1,-1}};

__device__ __forceinline__ int sw(int j){ return j ^ ((j >> 4) & 15); }

// one thread per TET: 6 keys (cross bit embedded) + occ nibble into NUMT region
__global__ void k_pack(const int* __restrict__ tet, const float* __restrict__ sdf,
                       u64* __restrict__ dst, float* __restrict__ occF){
  int t = blockIdx.x*blockDim.x + threadIdx.x;
  if (t >= NTET) return;
  int4 q = ((const int4*)tet)[t];
  int v[4] = {q.x, q.y, q.z, q.w};
  u32 o[4];
  int occ = 0;
  #pragma unroll
  for (int j=0;j<4;j++){ o[j] = sdf[v[j]] > 0.f ? 1u : 0u; occ |= (int)o[j] << j; }
  occF[t] = (float)occ;
  u64 base = (u64)t*6;
  #pragma unroll
  for (int k=0;k<6;k++){
    int a = v[c_ea[k]], b = v[c_eb[k]];
    u64 cross = (o[c_ea[k]] != o[c_eb[k]]) ? 1ull : 0ull;
    int e0 = min(a,b), e1 = max(a,b);
    u64 code = (u64)e0 * NVERT + (u64)e1;
    dst[base+k] = (code << CODESHIFT) | (cross << IDXBITS) | (base + (u64)k);
  }
}

__global__ void k_psd(const float* __restrict__ pos, const float* __restrict__ sdf,
                      float4* __restrict__ psd){
  int v = blockIdx.x*blockDim.x + threadIdx.x;
  if (v < NVERT) psd[v] = make_float4(pos[3*v], pos[3*v+1], pos[3*v+2], sdf[v]);
}

__global__ void k_fillm1(float4* __restrict__ p, int n4){
  int i = blockIdx.x*blockDim.x + threadIdx.x;
  if (i < n4) p[i] = make_float4(-1.f,-1.f,-1.f,-1.f);
}

__global__ __launch_bounds__(256) void k_hist(const u64* __restrict__ src, u32* __restrict__ hist, int shift){
  __shared__ u32 h[RBINS];
  int tid = threadIdx.x;
  #pragma unroll
  for (int r=0;r<RBINS/256;r++) h[tid + r*256] = 0;
  __syncthreads();
  int base = blockIdx.x * TILE;
  for (int k=0;k<16;k++){
    int i = base + k*256 + tid;
    if (i < NE) atomicAdd(&h[(u32)((src[i] >> shift) & (RBINS-1))], 1u);
  }
  __syncthreads();
  #pragma unroll
  for (int r=0;r<RBINS/256;r++){
    int d = tid + r*256;
    hist[(size_t)d * NTILES + blockIdx.x] = h[d];
  }
}

// per-digit exclusive scan across tiles (in place), digit totals out; grid = RBINS
__global__ void k_scan_digit(u32* __restrict__ hist, u32* __restrict__ digitTot){
  __shared__ u32 s[256];
  int d = blockIdx.x, tid = threadIdx.x;
  u32* row = hist + (size_t)d * NTILES;
  u32 carry = 0;
  for (int start=0; start<NTILES; start+=256){
    int idx = start + tid;
    u32 x = (idx < NTILES) ? row[idx] : 0;
    s[tid] = x; __syncthreads();
    for (int off=1; off<256; off<<=1){
      u32 t = (tid >= off) ? s[tid-off] : 0;
      __syncthreads();
      s[tid] += t;
      __syncthreads();
    }
    u32 incl = s[tid];
    u32 tot  = s[255];
    if (idx < NTILES) row[idx] = carry + incl - x;
    carry += tot;
    __syncthreads();
  }
  if (tid==0) digitTot[d] = carry;
}

__global__ __launch_bounds__(1024) void k_scan_base(const u32* __restrict__ digitTot, u32* __restrict__ digitOff){
  __shared__ u32 s[RBINS];
  int tid = threadIdx.x;
  u32 x = digitTot[tid];
  s[tid]=x; __syncthreads();
  for (int off=1; off<RBINS; off<<=1){
    u32 t=(tid>=off)?s[tid-off]:0;
    __syncthreads();
    s[tid]+=t;
    __syncthreads();
  }
  digitOff[tid] = s[tid]-x;
}

__global__ __launch_bounds__(256) void k_scatter(const u64* __restrict__ src, u64* __restrict__ dst,
      const u32* __restrict__ hist, const u32* __restrict__ digitOff, int shift){
  __shared__ u64 keys[TILE];
  __shared__ u32 sc[256];
  __shared__ u32 lstart[RBINS];
  int tid = threadIdx.x;
  int base = blockIdx.x * TILE;
  for (int k=0;k<16;k++){
    int j = k*256 + tid;
    int i = base + j;
    keys[sw(j)] = (i < NE) ? src[i] : ~0ull;
  }
  __syncthreads();
  for (int q=0;q<RBITS;q++){
    int sh = shift + q;
    u64 myk[16];
    u32 ones = 0, mask = 0;
    #pragma unroll
    for (int k=0;k<16;k++){
      myk[k] = keys[sw(tid*16+k)];
      u32 b = (u32)((myk[k] >> sh) & 1);
      mask |= b << k;
      ones += b;
    }
    sc[tid] = ones; __syncthreads();
    for (int off=1; off<256; off<<=1){
      u32 t=(tid>=off)?sc[tid-off]:0;
      __syncthreads();
      sc[tid]+=t;
      __syncthreads();
    }
    u32 incl = sc[tid];
    u32 totalOnes = sc[255];
    __syncthreads();
    u32 onesBefore = incl - ones;
    u32 zerosBefore = (u32)(tid*16) - onesBefore;
    u32 Z = TILE - totalOnes;
    #pragma unroll
    for (int k=0;k<16;k++){
      u32 pos;
      if ((mask>>k)&1u){ pos = Z + onesBefore; onesBefore++; }
      else { pos = zerosBefore; zerosBefore++; }
      keys[sw((int)pos)] = myk[k];
    }
    __syncthreads();
  }
  for (int k=0;k<16;k++){
    int j = k*256+tid;
    u32 d = (u32)((keys[sw(j)] >> shift) & (RBINS-1));
    bool headj = (j==0) || (((keys[sw(j-1)] >> shift) & (RBINS-1)) != d);
    if (headj) lstart[d] = (u32)j;
  }
  __syncthreads();
  for (int k=0;k<16;k++){
    int j = k*256+tid;
    u64 key = keys[sw(j)];
    if (key == ~0ull) continue;
    u32 d = (u32)((key >> shift) & (RBINS-1));
    u32 gpos = digitOff[d] + hist[(size_t)d*NTILES + blockIdx.x] + (u32)j - lstart[d];
    dst[gpos] = key;
  }
}

// fused post-sort pass: decoupled lookback + LDS-staged crossing-only pairs
__global__ __launch_bounds__(256) void k_emit_all(const u64* __restrict__ A,
     const float4* __restrict__ psd, u64* __restrict__ lb,
     u64* __restrict__ pairs, u32* __restrict__ cursors,
     float* __restrict__ verts, float* __restrict__ crossing_out){
  __shared__ u64 s[256];
  __shared__ u32 cnt[NBUCK], lcur[NBUCK];
  __shared__ u32 lofs[NBUCK+1];
  __shared__ u32 gbase[NBUCK];
  __shared__ u32 pscan[128];
  __shared__ u64 stage[TILE];
  __shared__ u64 bcast;
  int tid=threadIdx.x, blk=blockIdx.x;
  int start = blk*TILE + tid*16;
  if (tid < NBUCK){ cnt[tid]=0; lcur[tid]=0; }
  u64 prev = (start > 0 && start <= NE) ? A[start-1] : ~0ull;
  u64 myk[16];
  u32 headm=0, crossm=0;
  #pragma unroll
  for (int k=0;k<16;k++){
    int i = start + k;
    u64 v = 0;
    if (i<NE){
      v = A[i];
      if ((v>>CODESHIFT) != (prev>>CODESHIFT)) headm |= 1u<<k;
      if ((v>>IDXBITS) & 1ull) crossm |= 1u<<k;
      prev = v;
    }
    myk[k]=v;
  }
  __syncthreads();
  // crossing-only bucket counts
  #pragma unroll
  for (int k=0;k<16;k++){
    if ((start+k) < NE && ((crossm>>k)&1u))
      atomicAdd(&cnt[((u32)myk[k] & IDXMASK)>>BSHIFT], 1u);
  }
  u32 th = __popc(headm), tc = __popc(headm & crossm);
  u64 x = ((u64)th<<32)|(u64)tc;
  s[tid]=x; __syncthreads();
  for (int off=1;off<256;off<<=1){
    u64 t=(tid>=off)?s[tid-off]:0;
    __syncthreads();
    s[tid]+=t;
    __syncthreads();
  }
  u64 excl = s[tid]-x;
  u64 tot  = s[255];
  if (tid==255){
    u32 thT=(u32)(tot>>32), tcT=(u32)tot;
    u64 pth=0, ptc=0;
    if (blk==0){
      atomicExch(&lb[0], (2ull<<62)|((u64)thT<<23)|(u64)tcT);
    } else {
      atomicExch(&lb[blk], (1ull<<62)|((u64)thT<<23)|(u64)tcT);
      int p=blk-1;
      while (true){
        u64 v = atomicAdd(&lb[p], 0ull);
        u64 st = v>>62;
        if (st==0){ __builtin_amdgcn_s_sleep(1); continue; }
        pth += (v>>23)&0x7FFFFFull;
        ptc += v & 0x7FFFFFull;
        if (st==2) break;
        p--;
      }
      atomicExch(&lb[blk], (2ull<<62)|((u64)(thT+(u32)pth)<<23)|(u64)(tcT+(u32)ptc));
    }
    bcast = (pth<<32)|ptc;
  }
  __syncthreads();
  // bucket prefix over NBUCK (inclusive scan in pscan)
  if (tid < 128) pscan[tid] = (tid < NBUCK) ? cnt[tid] : 0;
  __syncthreads();
  for (int off=1; off<128; off<<=1){
    u32 t = 0;
    if (tid < 128 && tid >= off) t = pscan[tid-off];
    __syncthreads();
    if (tid < 128) pscan[tid] += t;
    __syncthreads();
  }
  if (tid < NBUCK) lofs[tid] = pscan[tid] - cnt[tid];
  if (tid == 0) lofs[NBUCK] = pscan[127];
  if (tid < NBUCK) gbase[tid] = atomicAdd(&cursors[tid], cnt[tid]);
  __syncthreads();
  u64 pfx = bcast;
  u32 H = (u32)(pfx>>32) + (u32)(excl>>32);
  u32 C = (u32)pfx + (u32)excl;
  #pragma unroll
  for (int k=0;k<16;k++){
    int i = start+k;
    if (i>=NE) break;
    bool head  = (headm>>k)&1u;
    bool cross = (crossm>>k)&1u;
    if (head){ H++; if(cross) C++; }
    if (cross){
      int m = (int)C-1;
      u32 orig = (u32)myk[k] & IDXMASK;
      u32 b = orig>>BSHIFT;
      u32 lp = lofs[b] + atomicAdd(&lcur[b], 1u);
      stage[lp] = ((u64)orig<<32) | (u64)(u32)m;
    }
    if (head){
      crossing_out[H-1] = cross ? 1.f : 0.f;
      if (cross){
        int m = (int)C-1;
        u64 code = myk[k]>>CODESHIFT;
        u32 u0=(u32)(code/NVERT), u1=(u32)(code%NVERT);
        float4 a = psd[u0], bb = psd[u1];
        float denom = a.w - bb.w;
        float w0 = (-bb.w)/denom, w1 = a.w/denom;
        verts[3*m+0] = a.x*w0 + bb.x*w1;
        verts[3*m+1] = a.y*w0 + bb.y*w1;
        verts[3*m+2] = a.z*w0 + bb.z*w1;
      }
    }
  }
  __syncthreads();
  // burst copy-out: contiguous run per bucket
  int ncross = (int)lofs[NBUCK];
  for (int j = tid; j < ncross; j += 256){
    int lo=0, hi=NBUCK;
    while (hi - lo > 1){ int mid=(lo+hi)>>1; if ((int)lofs[mid] <= j) lo=mid; else hi=mid; }
    pairs[(size_t)lo*BSZ + gbase[lo] + (u32)(j - (int)lofs[lo])] = stage[j];
  }
}

// per-bucket scatter of mapping into L2-resident 256KB window; count from cursors
__global__ void k_map_scatter(const u64* __restrict__ pairs, const u32* __restrict__ cursors,
                              float* __restrict__ mapF){
  int b = blockIdx.x / BPB, sub = blockIdx.x % BPB;
  u32 n = cursors[b];
  const u64* p = pairs + (size_t)b*BSZ;
  for (u32 i = (u32)(sub*256 + threadIdx.x); i < n; i += BPB*256){
    u64 v = p[i];
    mapF[(u32)(v>>32)] = (float)(int)(u32)v;
  }
}

// occF (== numt region) read, then overwritten per-element by the same thread
__global__ void k_faces(const float* __restrict__ occF, float* faceRegion, float* __restrict__ numt){
  int t = blockIdx.x*blockDim.x + threadIdx.x;
  if (t>=NTET) return;
  int occ = (int)occF[t];
  int ntri = c_numtri[occ];
  float em[6];
  #pragma unroll
  for (int j=0;j<6;j++) em[j] = faceRegion[t*6+j];
  float f[6];
  #pragma unroll
  for (int j=0;j<6;j++){
    int tri = c_tritab[occ][j];
    f[j] = ((j/3) < ntri) ? em[tri] : -1.f;
  }
  #pragma unroll
  for (int j=0;j<6;j++) faceRegion[t*6+j] = f[j];
  numt[t] = (float)ntri;
}

extern "C" void kernel_launch(void* const* d_in, const int* in_sizes, int n_in,
                              void* d_out, int out_size, void* d_ws, size_t ws_size,
                              hipStream_t stream) {
  const float* pos = (const float*)d_in[0];
  const float* sdf = (const float*)d_in[1];
  const int*   tet = (const int*)d_in[2];
  float* out = (float*)d_out;

  // ws layout (hist aliases pairs region: disjoint lifetimes)
  char* w = (char*)d_ws;
  u64* bufA     = (u64*)w;                         // 57,600,000
  u32* digitTot = (u32*)(w + 57600000);            // 4096
  u32* digitOff = (u32*)(w + 57604096);            // 4096
  u64* lb       = (u64*)(w + 57608192);            // 14,064
  u32* cursors  = (u32*)(w + 57622256);            // 448
  float4* psd   = (float4*)(w + 57622704);         // 4,800,000
  u64* pairs_ws = (u64*)(w + 62422784);            // 57,600,000 -> ends 120,022,784
  u32* hist     = (u32*)pairs_ws;                  // 7,200,768 (used only during sort)

  u64* bufB = (u64*)d_out;   // first 57.6MB of d_out as sort pong buffer

  k_pack<<<(NTET+255)/256, 256, 0, stream>>>(tet, sdf, bufA, out + NUMT_OFF);
  k_psd<<<(NVERT+255)/256, 256, 0, stream>>>(pos, sdf, psd);
  // faces region default -1.0f (non-crossing mapping); bytes 86.4MB..115.2MB of d_out — no overlap with bufB
  k_fillm1<<<(7200000/4 + 255)/256, 256, 0, stream>>>((float4*)(out + FACES_OFF), 7200000/4);

  u64 *src = bufA, *dst = bufB;
  for (int p=0; p<4; p++){
    int shift = SORT_BASE + RBITS*p;
    k_hist<<<NTILES, 256, 0, stream>>>(src, hist, shift);
    k_scan_digit<<<RBINS, 256, 0, stream>>>(hist, digitTot);
    k_scan_base<<<1, 1024, 0, stream>>>(digitTot, digitOff);
    k_scatter<<<NTILES, 256, 0, stream>>>(src, dst, hist, digitOff, shift);
    u64* tmp = src; src = dst; dst = tmp;
  }
  // 4 passes: bufA->bufB->bufA->bufB->bufA — sorted array in bufA (ws)

  hipMemsetAsync(out + VERTS_OFF, 0, (size_t)21600000*4, stream);
  hipMemsetAsync(out + CROSS_OFF, 0, (size_t)7200000*4, stream);
  hipMemsetAsync(cursors, 0, NBUCK*sizeof(u32), stream);
  hipMemsetAsync(lb, 0, (size_t)NTILES*8, stream);

  k_emit_all<<<NTILES, 256, 0, stream>>>(bufA, psd, lb, pairs_ws, cursors,
                                         out + VERTS_OFF, out + CROSS_OFF);
  k_map_scatter<<<NBUCK*BPB, 256, 0, stream>>>(pairs_ws, cursors, out + FACES_OFF);
  k_faces<<<(NTET+255)/256, 256, 0, stream>>>(out + NUMT_OFF, out + FACES_OFF, out + NUMT_OFF);
}